// Round 1
// baseline (886.104 us; speedup 1.0000x reference)
//
#include <hip/hip_runtime.h>
#include <hip/hip_bf16.h>
#include <stdint.h>

#define NS 2048   // n_seq
#define NR 512    // n_res
#define CI 64     // c_in
#define HH 8
#define CC 8

// ---------- helpers ----------
__device__ __forceinline__ unsigned pack_bf16x2(float a, float b) {
  unsigned ua = __float_as_uint(a), ub = __float_as_uint(b);
  ua += 0x7fffu + ((ua >> 16) & 1u);
  ub += 0x7fffu + ((ub >> 16) & 1u);
  return (ua >> 16) | (ub & 0xffff0000u);
}
__device__ __forceinline__ float bf_lo(unsigned u) { return __uint_as_float(u << 16); }
__device__ __forceinline__ float bf_hi(unsigned u) { return __uint_as_float(u & 0xffff0000u); }

template <int CTRL>
__device__ __forceinline__ float dpp_add_f(float v) {
  int s = __builtin_amdgcn_update_dpp(0, __float_as_int(v), CTRL, 0xf, 0xf, true);
  return v + __int_as_float(s);
}
// full sum broadcast to all 16 lanes of each DPP row (row_ror 8,4,2,1)
__device__ __forceinline__ float reduce16_all(float v) {
  v = dpp_add_f<0x128>(v);
  v = dpp_add_f<0x124>(v);
  v = dpp_add_f<0x122>(v);
  v = dpp_add_f<0x121>(v);
  return v;
}
// full sum lands in lane 15 of each 16-lane row (row_shr 1,2,4,8)
__device__ __forceinline__ float reduce16_lane15(float v) {
  v = dpp_add_f<0x111>(v);
  v = dpp_add_f<0x112>(v);
  v = dpp_add_f<0x114>(v);
  v = dpp_add_f<0x118>(v);
  return v;
}

// ---------- workspace layout (bytes) ----------
//  x_ws   : bf16 [NR][NS][CI]            = 128 MB
//  kv_ws  : f32  [NR][NS][16] (k|v)      =  64 MB
//  bias_ws: f32  [NR][NS]                =   4 MB
//  qpart  : f32  [NR][32][66]            ≈ 4.3 MB
//  o_ws   : f32  [NR][64]                = 128 KB
constexpr size_t X_BYTES    = (size_t)NR * NS * CI * 2;
constexpr size_t KV_OFF     = X_BYTES;
constexpr size_t KV_BYTES   = (size_t)NR * NS * 16 * 4;
constexpr size_t BIAS_OFF   = KV_OFF + KV_BYTES;
constexpr size_t BIAS_BYTES = (size_t)NR * NS * 4;
constexpr size_t QP_OFF     = BIAS_OFF + BIAS_BYTES;
constexpr size_t QP_BYTES   = (size_t)NR * 32 * 66 * 4;
constexpr size_t O_OFF      = QP_OFF + QP_BYTES;

// =====================================================================
// K1: LayerNorm + k/v projection + masked q partial sums + bias + x(bf16)
// grid (32 chunks, 512 r), 256 threads.  Each block: 64 rows of one r.
// =====================================================================
__global__ __launch_bounds__(256) void k1_ln_kv(
    const float* __restrict__ m, const float* __restrict__ mask,
    const float* __restrict__ lnw, const float* __restrict__ lnb,
    const float* __restrict__ wk, const float* __restrict__ wv,
    unsigned short* __restrict__ x_ws, float* __restrict__ kv_ws,
    float* __restrict__ bias_ws, float* __restrict__ qpart_ws)
{
  const int chunk = blockIdx.x, r = blockIdx.y;
  const int t = threadIdx.x;
  const int row16 = t >> 4, lane16 = t & 15;

  // per-thread rows of [w_k | w_v] for i = lane16*4 .. +3  (64 VGPRs)
  float wkvr[4][16];
#pragma unroll
  for (int il = 0; il < 4; ++il) {
    const float* wkp = wk + (size_t)(lane16 * 4 + il) * 8;
    const float* wvp = wv + (size_t)(lane16 * 4 + il) * 8;
#pragma unroll
    for (int c = 0; c < 8; ++c) { wkvr[il][c] = wkp[c]; wkvr[il][8 + c] = wvp[c]; }
  }
  const float4 lw = *(const float4*)(lnw + lane16 * 4);
  const float4 lb = *(const float4*)(lnb + lane16 * 4);

  float qacc0 = 0.f, qacc1 = 0.f, qacc2 = 0.f, qacc3 = 0.f, macc = 0.f;

#pragma unroll
  for (int it = 0; it < 4; ++it) {
    const int n = chunk * 64 + it * 16 + row16;
    const size_t mi = (size_t)n * NR + r;
    const float4 mv = *(const float4*)(m + mi * CI + lane16 * 4);

    float s1 = mv.x + mv.y + mv.z + mv.w;
    float s2 = mv.x * mv.x + mv.y * mv.y + mv.z * mv.z + mv.w * mv.w;
    s1 = reduce16_all(s1);
    s2 = reduce16_all(s2);
    const float mu = s1 * (1.0f / CI);
    const float var = fmaxf(s2 * (1.0f / CI) - mu * mu, 0.0f);
    const float rstd = rsqrtf(var + 1e-5f);

    const float x0 = (mv.x - mu) * rstd * lw.x + lb.x;
    const float x1 = (mv.y - mu) * rstd * lw.y + lb.y;
    const float x2 = (mv.z - mu) * rstd * lw.z + lb.z;
    const float x3 = (mv.w - mu) * rstd * lw.w + lb.w;

    const float mk = mask[mi];
    if (lane16 == 0) bias_ws[(size_t)r * NS + n] = 1e9f * (mk - 1.0f);

    *(uint2*)(x_ws + ((size_t)r * NS + n) * CI + lane16 * 4) =
        make_uint2(pack_bf16x2(x0, x1), pack_bf16x2(x2, x3));

    qacc0 += x0 * mk; qacc1 += x1 * mk; qacc2 += x2 * mk; qacc3 += x3 * mk;
    macc += mk;

    // k,v partials over this thread's 4 i-columns, then DPP tree-reduce
    float pk[16];
#pragma unroll
    for (int c = 0; c < 16; ++c)
      pk[c] = x0 * wkvr[0][c] + x1 * wkvr[1][c] + x2 * wkvr[2][c] + x3 * wkvr[3][c];
#pragma unroll
    for (int c = 0; c < 16; ++c) pk[c] = reduce16_lane15(pk[c]);

    if (lane16 == 15) {
      float* dst = kv_ws + ((size_t)r * NS + n) * 16;
      *(float4*)(dst + 0)  = make_float4(pk[0],  pk[1],  pk[2],  pk[3]);
      *(float4*)(dst + 4)  = make_float4(pk[4],  pk[5],  pk[6],  pk[7]);
      *(float4*)(dst + 8)  = make_float4(pk[8],  pk[9],  pk[10], pk[11]);
      *(float4*)(dst + 12) = make_float4(pk[12], pk[13], pk[14], pk[15]);
    }
  }

  // reduce masked-x partials across the 16 row-groups
  __shared__ float qred[16][64];
  __shared__ float mred[16];
  qred[row16][lane16 * 4 + 0] = qacc0;
  qred[row16][lane16 * 4 + 1] = qacc1;
  qred[row16][lane16 * 4 + 2] = qacc2;
  qred[row16][lane16 * 4 + 3] = qacc3;
  if (lane16 == 0) mred[row16] = macc;
  __syncthreads();
  if (t < 64) {
    float s = 0.f;
#pragma unroll
    for (int g = 0; g < 16; ++g) s += qred[g][t];
    qpart_ws[((size_t)r * 32 + chunk) * 66 + t] = s;
  } else if (t == 64) {
    float s = 0.f;
#pragma unroll
    for (int g = 0; g < 16; ++g) s += mred[g];
    qpart_ws[((size_t)r * 32 + chunk) * 66 + 64] = s;
  }
}

// =====================================================================
// K2: q finalize + flash attention over n -> o[r][64]
// grid (512), 256 threads (8 head-groups x 32 lanes)
// =====================================================================
__global__ __launch_bounds__(256) void k2_attn(
    const float* __restrict__ wq, const float* __restrict__ kv_ws,
    const float* __restrict__ bias_ws, const float* __restrict__ qpart_ws,
    float* __restrict__ o_ws)
{
  const int r = blockIdx.x, t = threadIdx.x;
  __shared__ float qavg_s[64], q_s[64], msum_s;
  __shared__ float kv_s[256][20];   // 20-float stride: 16B-aligned rows
  __shared__ float bias_s[256];

  float qsum = 0.f;
  if (t < 64) {
    for (int ch = 0; ch < 32; ++ch) qsum += qpart_ws[((size_t)r * 32 + ch) * 66 + t];
  } else if (t == 64) {
    float s = 0.f;
    for (int ch = 0; ch < 32; ++ch) s += qpart_ws[((size_t)r * 32 + ch) * 66 + 64];
    msum_s = s;
  }
  __syncthreads();
  if (t < 64) qavg_s[t] = qsum / (msum_s + 1e-10f);
  __syncthreads();
  if (t < 64) {
    float a = 0.f;
    for (int i = 0; i < 64; ++i) a += qavg_s[i] * wq[(size_t)i * 64 + t];
    q_s[t] = a * 0.35355339059327373f;  // C^-0.5
  }
  __syncthreads();

  const int hg = t >> 5, lid = t & 31;
  float q8[8];
#pragma unroll
  for (int c = 0; c < 8; ++c) q8[c] = q_s[hg * 8 + c];

  float mrun = -3.0e38f, srun = 0.f;
  float oa[8] = {0.f, 0.f, 0.f, 0.f, 0.f, 0.f, 0.f, 0.f};

  for (int tile = 0; tile < 8; ++tile) {
    __syncthreads();
    const int n0 = tile * 256;
    const float4* src = (const float4*)(kv_ws + ((size_t)r * NS + n0 + t) * 16);
    const float4 s0 = src[0], s1 = src[1], s2 = src[2], s3 = src[3];
    *(float4*)&kv_s[t][0]  = s0;
    *(float4*)&kv_s[t][4]  = s1;
    *(float4*)&kv_s[t][8]  = s2;
    *(float4*)&kv_s[t][12] = s3;
    bias_s[t] = bias_ws[(size_t)r * NS + n0 + t];
    __syncthreads();
#pragma unroll
    for (int jj = 0; jj < 8; ++jj) {
      const int n = jj * 32 + lid;
      const float4 k0 = *(const float4*)&kv_s[n][0];
      const float4 k1 = *(const float4*)&kv_s[n][4];
      float lg = q8[0] * k0.x + q8[1] * k0.y + q8[2] * k0.z + q8[3] * k0.w
               + q8[4] * k1.x + q8[5] * k1.y + q8[6] * k1.z + q8[7] * k1.w
               + bias_s[n];
      const float mnew = fmaxf(mrun, lg);
      const float sc = __expf(mrun - mnew);
      const float p  = __expf(lg - mnew);
      const float4 v0 = *(const float4*)&kv_s[n][8];
      const float4 v1 = *(const float4*)&kv_s[n][12];
      srun = srun * sc + p;
      oa[0] = oa[0] * sc + p * v0.x;
      oa[1] = oa[1] * sc + p * v0.y;
      oa[2] = oa[2] * sc + p * v0.z;
      oa[3] = oa[3] * sc + p * v0.w;
      oa[4] = oa[4] * sc + p * v1.x;
      oa[5] = oa[5] * sc + p * v1.y;
      oa[6] = oa[6] * sc + p * v1.z;
      oa[7] = oa[7] * sc + p * v1.w;
      mrun = mnew;
    }
  }

  // merge the 32 lanes of this head-group
#pragma unroll
  for (int off = 16; off >= 1; off >>= 1) {
    const float mo = __shfl_xor(mrun, off);
    const float so = __shfl_xor(srun, off);
    float ox[8];
#pragma unroll
    for (int c = 0; c < 8; ++c) ox[c] = __shfl_xor(oa[c], off);
    const float mn = fmaxf(mrun, mo);
    const float e0 = __expf(mrun - mn), e1 = __expf(mo - mn);
    srun = srun * e0 + so * e1;
#pragma unroll
    for (int c = 0; c < 8; ++c) oa[c] = oa[c] * e0 + ox[c] * e1;
    mrun = mn;
  }
  if (lid == 0) {
    const float inv = 1.0f / srun;
#pragma unroll
    for (int c = 0; c < 8; ++c) o_ws[(size_t)r * 64 + hg * 8 + c] = oa[c] * inv;
  }
}

// =====================================================================
// K3: g = sigmoid(x@w_g + b_g); out = (g*o)@w_o + b_o   (two 64x64 GEMMs)
// grid (8 chunks, 512 r), 256 threads; 256-row tile; 8x8 register tiles.
// =====================================================================
__global__ __launch_bounds__(256) void k3_out(
    const unsigned short* __restrict__ x_ws, const float* __restrict__ o_ws,
    const float* __restrict__ wg, const float* __restrict__ bg,
    const float* __restrict__ wo, const float* __restrict__ bo,
    float* __restrict__ out)
{
  const int chunk = blockIdx.x, r = blockIdx.y, t = threadIdx.x;
  __shared__ unsigned short xbuf[256][68];   // x tile, then reused for og
  __shared__ unsigned short wg_s[64][64];
  __shared__ unsigned short wo_s[64][64];

  // stage weights as bf16 (16 contiguous values per thread)
  {
    const float* g1 = wg + t * 16;
    const float* g2 = wo + t * 16;
    unsigned short* d1 = &wg_s[0][0] + t * 16;
    unsigned short* d2 = &wo_s[0][0] + t * 16;
    uint4 a, b;
    a.x = pack_bf16x2(g1[0], g1[1]);   a.y = pack_bf16x2(g1[2], g1[3]);
    a.z = pack_bf16x2(g1[4], g1[5]);   a.w = pack_bf16x2(g1[6], g1[7]);
    b.x = pack_bf16x2(g1[8], g1[9]);   b.y = pack_bf16x2(g1[10], g1[11]);
    b.z = pack_bf16x2(g1[12], g1[13]); b.w = pack_bf16x2(g1[14], g1[15]);
    *(uint4*)d1 = a; *(uint4*)(d1 + 8) = b;
    a.x = pack_bf16x2(g2[0], g2[1]);   a.y = pack_bf16x2(g2[2], g2[3]);
    a.z = pack_bf16x2(g2[4], g2[5]);   a.w = pack_bf16x2(g2[6], g2[7]);
    b.x = pack_bf16x2(g2[8], g2[9]);   b.y = pack_bf16x2(g2[10], g2[11]);
    b.z = pack_bf16x2(g2[12], g2[13]); b.w = pack_bf16x2(g2[14], g2[15]);
    *(uint4*)d2 = a; *(uint4*)(d2 + 8) = b;
  }
  // stage x tile: thread t owns row t (128B streaming load)
  {
    const uint4* src = (const uint4*)(x_ws + ((size_t)r * NS + (size_t)chunk * 256 + t) * CI);
#pragma unroll
    for (int qd = 0; qd < 8; ++qd) *(uint4*)&xbuf[t][qd * 8] = src[qd];
  }

  const int rgrp = t >> 3, cgrp = t & 7;   // rows rgrp+32k, cols cgrp*8..+7
  float orv[8], bgv[8], bov[8];
#pragma unroll
  for (int j = 0; j < 8; ++j) {
    orv[j] = o_ws[(size_t)r * 64 + cgrp * 8 + j];
    bgv[j] = bg[cgrp * 8 + j];
    bov[j] = bo[cgrp * 8 + j];
  }
  __syncthreads();

  // ---- GEMM1: acc = x @ w_g ----
  float acc[8][8];
#pragma unroll
  for (int k = 0; k < 8; ++k)
#pragma unroll
    for (int j = 0; j < 8; ++j) acc[k][j] = 0.f;

  for (int i4 = 0; i4 < 16; ++i4) {
    float wf[4][8];
#pragma unroll
    for (int ii = 0; ii < 4; ++ii) {
      const uint4 wv4 = *(const uint4*)&wg_s[i4 * 4 + ii][cgrp * 8];
      wf[ii][0] = bf_lo(wv4.x); wf[ii][1] = bf_hi(wv4.x);
      wf[ii][2] = bf_lo(wv4.y); wf[ii][3] = bf_hi(wv4.y);
      wf[ii][4] = bf_lo(wv4.z); wf[ii][5] = bf_hi(wv4.z);
      wf[ii][6] = bf_lo(wv4.w); wf[ii][7] = bf_hi(wv4.w);
    }
#pragma unroll
    for (int k = 0; k < 8; ++k) {
      const uint2 xv = *(const uint2*)&xbuf[rgrp + 32 * k][i4 * 4];
      const float x0 = bf_lo(xv.x), x1 = bf_hi(xv.x);
      const float x2 = bf_lo(xv.y), x3 = bf_hi(xv.y);
#pragma unroll
      for (int j = 0; j < 8; ++j)
        acc[k][j] += x0 * wf[0][j] + x1 * wf[1][j] + x2 * wf[2][j] + x3 * wf[3][j];
    }
  }
  __syncthreads();   // all xbuf reads done

  // ---- og = sigmoid(acc + b_g) * o  -> bf16 back into xbuf ----
#pragma unroll
  for (int k = 0; k < 8; ++k) {
    float og[8];
#pragma unroll
    for (int j = 0; j < 8; ++j) {
      const float z = acc[k][j] + bgv[j];
      og[j] = (1.0f / (1.0f + __expf(-z))) * orv[j];
    }
    uint4 w4;
    w4.x = pack_bf16x2(og[0], og[1]); w4.y = pack_bf16x2(og[2], og[3]);
    w4.z = pack_bf16x2(og[4], og[5]); w4.w = pack_bf16x2(og[6], og[7]);
    *(uint4*)&xbuf[rgrp + 32 * k][cgrp * 8] = w4;
  }
  __syncthreads();

  // ---- GEMM2: out = og @ w_o + b_o ----
  float acc2[8][8];
#pragma unroll
  for (int k = 0; k < 8; ++k)
#pragma unroll
    for (int j = 0; j < 8; ++j) acc2[k][j] = 0.f;

  for (int i4 = 0; i4 < 16; ++i4) {
    float wf[4][8];
#pragma unroll
    for (int ii = 0; ii < 4; ++ii) {
      const uint4 wv4 = *(const uint4*)&wo_s[i4 * 4 + ii][cgrp * 8];
      wf[ii][0] = bf_lo(wv4.x); wf[ii][1] = bf_hi(wv4.x);
      wf[ii][2] = bf_lo(wv4.y); wf[ii][3] = bf_hi(wv4.y);
      wf[ii][4] = bf_lo(wv4.z); wf[ii][5] = bf_hi(wv4.z);
      wf[ii][6] = bf_lo(wv4.w); wf[ii][7] = bf_hi(wv4.w);
    }
#pragma unroll
    for (int k = 0; k < 8; ++k) {
      const uint2 xv = *(const uint2*)&xbuf[rgrp + 32 * k][i4 * 4];
      const float x0 = bf_lo(xv.x), x1 = bf_hi(xv.x);
      const float x2 = bf_lo(xv.y), x3 = bf_hi(xv.y);
#pragma unroll
      for (int j = 0; j < 8; ++j)
        acc2[k][j] += x0 * wf[0][j] + x1 * wf[1][j] + x2 * wf[2][j] + x3 * wf[3][j];
    }
  }

  // ---- store: out[n][r][p] ----
#pragma unroll
  for (int k = 0; k < 8; ++k) {
    const int n = chunk * 256 + rgrp + 32 * k;
    float* dst = out + ((size_t)n * NR + r) * CI + cgrp * 8;
    *(float4*)(dst)     = make_float4(acc2[k][0] + bov[0], acc2[k][1] + bov[1],
                                      acc2[k][2] + bov[2], acc2[k][3] + bov[3]);
    *(float4*)(dst + 4) = make_float4(acc2[k][4] + bov[4], acc2[k][5] + bov[5],
                                      acc2[k][6] + bov[6], acc2[k][7] + bov[7]);
  }
}

// =====================================================================
extern "C" void kernel_launch(void* const* d_in, const int* in_sizes, int n_in,
                              void* d_out, int out_size, void* d_ws, size_t ws_size,
                              hipStream_t stream) {
  const float* m    = (const float*)d_in[0];
  const float* mask = (const float*)d_in[1];
  const float* lnw  = (const float*)d_in[2];
  const float* lnb  = (const float*)d_in[3];
  const float* wq   = (const float*)d_in[4];
  const float* wk   = (const float*)d_in[5];
  const float* wv   = (const float*)d_in[6];
  const float* wg   = (const float*)d_in[7];
  const float* bg   = (const float*)d_in[8];
  const float* wo   = (const float*)d_in[9];
  const float* bo   = (const float*)d_in[10];
  float* out = (float*)d_out;

  char* ws = (char*)d_ws;
  unsigned short* x_ws = (unsigned short*)ws;
  float* kv_ws   = (float*)(ws + KV_OFF);
  float* bias_ws = (float*)(ws + BIAS_OFF);
  float* qpart   = (float*)(ws + QP_OFF);
  float* o_ws    = (float*)(ws + O_OFF);

  k1_ln_kv<<<dim3(32, 512), 256, 0, stream>>>(m, mask, lnw, lnb, wk, wv,
                                              x_ws, kv_ws, bias_ws, qpart);
  k2_attn<<<dim3(512), 256, 0, stream>>>(wq, kv_ws, bias_ws, qpart, o_ws);
  k3_out<<<dim3(8, 512), 256, 0, stream>>>(x_ws, o_ws, wg, bg, wo, bo, out);
}

// Round 4
// 580.710 us; speedup vs baseline: 1.5259x; 1.5259x over previous
//
#include <hip/hip_runtime.h>
#include <hip/hip_bf16.h>
#include <stdint.h>

#define NS 2048   // n_seq
#define NR 512    // n_res
#define CI 64     // c_in

typedef __attribute__((ext_vector_type(8))) short bf16x8;
typedef __attribute__((ext_vector_type(4))) float f32x4;

// ---------- helpers ----------
__device__ __forceinline__ unsigned pack_bf16x2(float a, float b) {
  unsigned ua = __float_as_uint(a), ub = __float_as_uint(b);
  ua += 0x7fffu + ((ua >> 16) & 1u);
  ub += 0x7fffu + ((ub >> 16) & 1u);
  return (ua >> 16) | (ub & 0xffff0000u);
}
__device__ __forceinline__ unsigned short bf16r(float a) {
  unsigned ua = __float_as_uint(a);
  ua += 0x7fffu + ((ua >> 16) & 1u);
  return (unsigned short)(ua >> 16);
}
__device__ __forceinline__ float bf2f(unsigned short u) {
  return __uint_as_float(((unsigned)u) << 16);
}
// swizzled ushort index into a [rows][64] bf16 tile (128B rows, XOR of 16B chunk
// index with row&7 -> <=2-way LDS bank aliasing on both b128 reads and writes)
__device__ __forceinline__ int swz(int row, int chunk) {
  return row * 64 + ((chunk ^ (row & 7)) << 3);
}

// ---------- workspace layout ----------
//  x_ws : bf16 [NR][NS][CI]        128 MB
//  kv_ws: f32  [NR][NS][16]         64 MB
//  qp_ws: f32  [NR][8][65]          ~1 MB   (64 masked-x sums + msum per chunk)
//  o_ws : f32  [NR][64]            128 KB
constexpr size_t X_BYTES  = (size_t)NR * NS * CI * 2;
constexpr size_t KV_OFF   = X_BYTES;
constexpr size_t KV_BYTES = (size_t)NR * NS * 16 * 4;
constexpr size_t QP_OFF   = KV_OFF + KV_BYTES;
constexpr size_t QP_BYTES = (size_t)NR * 8 * 65 * 4;
constexpr size_t O_OFF    = QP_OFF + QP_BYTES;

// =====================================================================
// K1: row-per-lane LayerNorm -> x(bf16) ; kv via split-precision MFMA ;
//     q-partials from LDS x tile. grid (8, 512), 256 threads (4 waves).
// =====================================================================
__global__ __launch_bounds__(256, 2) void k1_ln_kv(
    const float* __restrict__ m, const float* __restrict__ mask,
    const float* __restrict__ lnw, const float* __restrict__ lnb,
    const float* __restrict__ wk, const float* __restrict__ wv,
    unsigned short* __restrict__ x_ws, float* __restrict__ kv_ws,
    float* __restrict__ qp_ws)
{
  const int chunk = blockIdx.x, r = blockIdx.y, t = threadIdx.x;
  const int n0 = chunk * 256;

  __shared__ unsigned short xs[256 * 64];    // 32 KB swizzled bf16(x)
  __shared__ unsigned short xls[256 * 64];   // 32 KB swizzled bf16(x - bf16(x))
  __shared__ unsigned short wh_s[16 * 64];   // [c=16][k=64] transposed wk|wv hi
  __shared__ unsigned short wl_s[16 * 64];   // lo split
  __shared__ float lwb_s[128];               // ln_w[64] | ln_b[64]
  __shared__ float mk_s[256];
  __shared__ float red_s[4 * 64 + 8];

  // 1. issue this lane's m row (strided reads, full-line utilization)
  float4 mv[16];
  const float4* mp = (const float4*)(m + ((size_t)(n0 + t) * NR + r) * CI);
#pragma unroll
  for (int i = 0; i < 16; ++i) mv[i] = mp[i];

  mk_s[t] = mask[(size_t)(n0 + t) * NR + r];
  const float mk_l = mk_s[t];

  // 2. stage transposed hi/lo weight splits + layernorm params
  if (t < 128) {
    const int c = t >> 3, kq = (t & 7) * 8;
    const float* wsrc = (c < 8) ? (wk + c) : (wv + (c - 8));
    const int o = swz(c, kq >> 3);
#pragma unroll
    for (int i = 0; i < 8; ++i) {
      const float w = wsrc[(size_t)(kq + i) * 8];
      const unsigned short hh = bf16r(w);
      wh_s[o + i] = hh;
      wl_s[o + i] = bf16r(w - bf2f(hh));
    }
  } else if (t < 192) {
    const int i = t - 128;
    lwb_s[i] = lnw[i];
    lwb_s[64 + i] = lnb[i];
  }
  __syncthreads();

  // 3. LN stats fully in registers (no cross-lane ops)
  float s1 = 0.f, s2 = 0.f;
#pragma unroll
  for (int i = 0; i < 16; ++i) {
    s1 += mv[i].x + mv[i].y + mv[i].z + mv[i].w;
    s2 += mv[i].x * mv[i].x + mv[i].y * mv[i].y + mv[i].z * mv[i].z + mv[i].w * mv[i].w;
  }
  const float mu = s1 * (1.0f / CI);
  const float var = fmaxf(s2 * (1.0f / CI) - mu * mu, 0.f);
  const float rstd = rsqrtf(var + 1e-5f);

  // 4. normalize, hi/lo split, write swizzled LDS tiles
#pragma unroll
  for (int i4 = 0; i4 < 16; ++i4) {
    const float4 lw = *(const float4*)&lwb_s[i4 * 4];
    const float4 lb = *(const float4*)&lwb_s[64 + i4 * 4];
    const float x0 = (mv[i4].x - mu) * rstd * lw.x + lb.x;
    const float x1 = (mv[i4].y - mu) * rstd * lw.y + lb.y;
    const float x2 = (mv[i4].z - mu) * rstd * lw.z + lb.z;
    const float x3 = (mv[i4].w - mu) * rstd * lw.w + lb.w;
    const unsigned h01 = pack_bf16x2(x0, x1), h23 = pack_bf16x2(x2, x3);
    const float e0 = x0 - __uint_as_float(h01 << 16);
    const float e1 = x1 - __uint_as_float(h01 & 0xffff0000u);
    const float e2 = x2 - __uint_as_float(h23 << 16);
    const float e3 = x3 - __uint_as_float(h23 & 0xffff0000u);
    const unsigned l01 = pack_bf16x2(e0, e1), l23 = pack_bf16x2(e2, e3);
    const int off = swz(t, i4 >> 1) + (i4 & 1) * 4;
    *(uint2*)&xs[off]  = make_uint2(h01, h23);
    *(uint2*)&xls[off] = make_uint2(l01, l23);
  }
  __syncthreads();

  // 5. kv = xh@wh + xl@wh + xh@wl  (f32-accurate via 3-way split MFMA)
  const int w = t >> 6, l = t & 63;
  const int lr = l & 15, lk = l >> 4;
  f32x4 acc[4];
#pragma unroll
  for (int mt = 0; mt < 4; ++mt) acc[mt] = (f32x4)(0.f);
  bf16x8 bh[2], bl[2];
#pragma unroll
  for (int ks = 0; ks < 2; ++ks) {
    bh[ks] = *(const bf16x8*)&wh_s[swz(lr, ks * 4 + lk)];
    bl[ks] = *(const bf16x8*)&wl_s[swz(lr, ks * 4 + lk)];
  }
#pragma unroll
  for (int mt = 0; mt < 4; ++mt) {
    const int row = w * 64 + mt * 16 + lr;
#pragma unroll
    for (int ks = 0; ks < 2; ++ks) {
      const bf16x8 ah = *(const bf16x8*)&xs[swz(row, ks * 4 + lk)];
      const bf16x8 al = *(const bf16x8*)&xls[swz(row, ks * 4 + lk)];
      acc[mt] = __builtin_amdgcn_mfma_f32_16x16x32_bf16(ah, bh[ks], acc[mt], 0, 0, 0);
      acc[mt] = __builtin_amdgcn_mfma_f32_16x16x32_bf16(al, bh[ks], acc[mt], 0, 0, 0);
      acc[mt] = __builtin_amdgcn_mfma_f32_16x16x32_bf16(ah, bl[ks], acc[mt], 0, 0, 0);
    }
  }
  // store kv: C/D layout col=lane&15, row=(lane>>4)*4+reg (verified m89/m91)
#pragma unroll
  for (int mt = 0; mt < 4; ++mt)
#pragma unroll
    for (int reg = 0; reg < 4; ++reg) {
      const int row = w * 64 + mt * 16 + lk * 4 + reg;
      kv_ws[((size_t)r * NS + n0 + row) * 16 + lr] = acc[mt][reg];
    }

  // 6. masked q-partials from the LDS x tile
  {
    const int c = t & 63, rg = t >> 6;
    const int jc = c >> 3, cw = c & 7;
    float qa = 0.f;
#pragma unroll 8
    for (int i = 0; i < 64; ++i) {
      const int row = rg * 64 + i;
      qa += bf2f(xs[row * 64 + ((jc ^ (row & 7)) << 3) + cw]) * mk_s[row];
    }
    red_s[rg * 64 + c] = qa;
    float ms = mk_l;
#pragma unroll
    for (int off = 32; off >= 1; off >>= 1) ms += __shfl_down(ms, off);
    if (l == 0) red_s[256 + w] = ms;
  }
  __syncthreads();
  if (t < 64) {
    const float s = red_s[t] + red_s[64 + t] + red_s[128 + t] + red_s[192 + t];
    qp_ws[((size_t)r * 8 + chunk) * 65 + t] = s;
  } else if (t == 64) {
    qp_ws[((size_t)r * 8 + chunk) * 65 + 64] =
        red_s[256] + red_s[257] + red_s[258] + red_s[259];
  }

  // 7. coalesced x store to global from LDS
#pragma unroll
  for (int it = 0; it < 8; ++it) {
    const int idx = it * 256 + t;
    const int row = idx >> 3, j = idx & 7;
    const uint4 v = *(const uint4*)&xs[swz(row, j)];
    *(uint4*)&x_ws[((size_t)r * NS + n0 + row) * CI + j * 8] = v;
  }
}

// =====================================================================
// K2: q finalize + flash attention over n -> o[r][64]. grid (512), 256 thr.
// =====================================================================
__global__ __launch_bounds__(256) void k2_attn(
    const float* __restrict__ mask, const float* __restrict__ wq,
    const float* __restrict__ kv_ws, const float* __restrict__ qp_ws,
    float* __restrict__ o_ws)
{
  const int r = blockIdx.x, t = threadIdx.x;
  __shared__ float mk_s[2048];
  __shared__ float qavg_s[64], q_s[64];
  __shared__ float msum_s;
  __shared__ float kv_s[256][20];

#pragma unroll
  for (int i = 0; i < 8; ++i) {
    const int n = t + 256 * i;
    mk_s[n] = mask[(size_t)n * NR + r];
  }
  if (t < 64) {
    float s = 0.f;
#pragma unroll
    for (int ch = 0; ch < 8; ++ch) s += qp_ws[((size_t)r * 8 + ch) * 65 + t];
    qavg_s[t] = s;
  } else if (t == 64) {
    float s = 0.f;
#pragma unroll
    for (int ch = 0; ch < 8; ++ch) s += qp_ws[((size_t)r * 8 + ch) * 65 + 64];
    msum_s = s;
  }
  __syncthreads();
  if (t < 64) {
    const float inv = 1.0f / (msum_s + 1e-10f);
    float a = 0.f;
    for (int i = 0; i < 64; ++i) a += (qavg_s[i] * inv) * wq[(size_t)i * 64 + t];
    q_s[t] = a * 0.35355339059327373f;  // C^-0.5
  }
  __syncthreads();

  const int hg = t >> 5, lid = t & 31;
  float q8[8];
#pragma unroll
  for (int c = 0; c < 8; ++c) q8[c] = q_s[hg * 8 + c];

  float mrun = -3.0e38f, srun = 0.f;
  float oa[8] = {0.f, 0.f, 0.f, 0.f, 0.f, 0.f, 0.f, 0.f};

  for (int tile = 0; tile < 8; ++tile) {
    __syncthreads();
    const int n0 = tile * 256;
    const float4* src = (const float4*)(kv_ws + ((size_t)r * NS + n0 + t) * 16);
    const float4 s0 = src[0], s1 = src[1], s2 = src[2], s3 = src[3];
    *(float4*)&kv_s[t][0]  = s0;
    *(float4*)&kv_s[t][4]  = s1;
    *(float4*)&kv_s[t][8]  = s2;
    *(float4*)&kv_s[t][12] = s3;
    __syncthreads();
#pragma unroll
    for (int jj = 0; jj < 8; ++jj) {
      const int n = jj * 32 + lid;
      const float4 k0 = *(const float4*)&kv_s[n][0];
      const float4 k1 = *(const float4*)&kv_s[n][4];
      float lg = q8[0] * k0.x + q8[1] * k0.y + q8[2] * k0.z + q8[3] * k0.w
               + q8[4] * k1.x + q8[5] * k1.y + q8[6] * k1.z + q8[7] * k1.w
               + 1e9f * (mk_s[n0 + n] - 1.0f);
      const float mnew = fmaxf(mrun, lg);
      const float sc = __expf(mrun - mnew);
      const float p  = __expf(lg - mnew);
      const float4 v0 = *(const float4*)&kv_s[n][8];
      const float4 v1 = *(const float4*)&kv_s[n][12];
      srun = srun * sc + p;
      oa[0] = oa[0] * sc + p * v0.x;  oa[1] = oa[1] * sc + p * v0.y;
      oa[2] = oa[2] * sc + p * v0.z;  oa[3] = oa[3] * sc + p * v0.w;
      oa[4] = oa[4] * sc + p * v1.x;  oa[5] = oa[5] * sc + p * v1.y;
      oa[6] = oa[6] * sc + p * v1.z;  oa[7] = oa[7] * sc + p * v1.w;
      mrun = mnew;
    }
  }
#pragma unroll
  for (int off = 16; off >= 1; off >>= 1) {
    const float mo = __shfl_xor(mrun, off);
    const float so = __shfl_xor(srun, off);
    float ox[8];
#pragma unroll
    for (int c = 0; c < 8; ++c) ox[c] = __shfl_xor(oa[c], off);
    const float mn = fmaxf(mrun, mo);
    const float e0 = __expf(mrun - mn), e1 = __expf(mo - mn);
    srun = srun * e0 + so * e1;
#pragma unroll
    for (int c = 0; c < 8; ++c) oa[c] = oa[c] * e0 + ox[c] * e1;
    mrun = mn;
  }
  if (lid == 0) {
    const float inv = 1.0f / srun;
#pragma unroll
    for (int c = 0; c < 8; ++c) o_ws[(size_t)r * 64 + hg * 8 + c] = oa[c] * inv;
  }
}

// =====================================================================
// K3: gate + output projection, both 64x64 GEMMs on MFMA.
// grid (8, 512), 256 threads (4 waves, 64 rows each).
// =====================================================================
__global__ __launch_bounds__(256, 2) void k3_out(
    const unsigned short* __restrict__ x_ws, const float* __restrict__ o_ws,
    const float* __restrict__ wg, const float* __restrict__ bg,
    const float* __restrict__ wo, const float* __restrict__ bo,
    float* __restrict__ out)
{
  const int chunk = blockIdx.x, r = blockIdx.y, t = threadIdx.x;
  const int n0 = chunk * 256;
  __shared__ unsigned short xs[256 * 64];   // x tile, later og tile (swizzled)
  __shared__ unsigned short wgT[64 * 64];   // [n][k] bf16 swizzled
  __shared__ unsigned short woT[64 * 64];

  // stage x tile (coalesced global reads, swizzled LDS writes)
#pragma unroll
  for (int it = 0; it < 8; ++it) {
    const int idx = it * 256 + t;
    const int row = idx >> 3, j = idx & 7;
    const uint4 v = *(const uint4*)&x_ws[((size_t)r * NS + n0 + row) * CI + j * 8];
    *(uint4*)&xs[swz(row, j)] = v;
  }
  // stage weights transposed into bf16 (each wave owns one 16-k group)
  {
    const int n = t & 63, kg = t >> 6;
    unsigned short tmp[16];
#pragma unroll
    for (int kk = 0; kk < 16; ++kk) tmp[kk] = bf16r(wg[(size_t)(kg * 16 + kk) * 64 + n]);
#pragma unroll
    for (int h = 0; h < 2; ++h) {
      uint4 u;
      u.x = (unsigned)tmp[h * 8 + 0] | ((unsigned)tmp[h * 8 + 1] << 16);
      u.y = (unsigned)tmp[h * 8 + 2] | ((unsigned)tmp[h * 8 + 3] << 16);
      u.z = (unsigned)tmp[h * 8 + 4] | ((unsigned)tmp[h * 8 + 5] << 16);
      u.w = (unsigned)tmp[h * 8 + 6] | ((unsigned)tmp[h * 8 + 7] << 16);
      *(uint4*)&wgT[swz(n, kg * 2 + h)] = u;
    }
#pragma unroll
    for (int kk = 0; kk < 16; ++kk) tmp[kk] = bf16r(wo[(size_t)(kg * 16 + kk) * 64 + n]);
#pragma unroll
    for (int h = 0; h < 2; ++h) {
      uint4 u;
      u.x = (unsigned)tmp[h * 8 + 0] | ((unsigned)tmp[h * 8 + 1] << 16);
      u.y = (unsigned)tmp[h * 8 + 2] | ((unsigned)tmp[h * 8 + 3] << 16);
      u.z = (unsigned)tmp[h * 8 + 4] | ((unsigned)tmp[h * 8 + 5] << 16);
      u.w = (unsigned)tmp[h * 8 + 6] | ((unsigned)tmp[h * 8 + 7] << 16);
      *(uint4*)&woT[swz(n, kg * 2 + h)] = u;
    }
  }

  const int w = t >> 6, l = t & 63, lr = l & 15, lk = l >> 4;
  float o4[4], bg4[4], bo4[4];
#pragma unroll
  for (int nt = 0; nt < 4; ++nt) {
    o4[nt]  = o_ws[(size_t)r * 64 + nt * 16 + lr];
    bg4[nt] = bg[nt * 16 + lr];
    bo4[nt] = bo[nt * 16 + lr];
  }
  __syncthreads();

  // GEMM1: z = x @ w_g
  f32x4 acc[4][4];
#pragma unroll
  for (int mt = 0; mt < 4; ++mt)
#pragma unroll
    for (int nt = 0; nt < 4; ++nt) acc[mt][nt] = (f32x4)(0.f);
#pragma unroll
  for (int nt = 0; nt < 4; ++nt) {
    const bf16x8 b0 = *(const bf16x8*)&wgT[swz(nt * 16 + lr, lk)];
    const bf16x8 b1 = *(const bf16x8*)&wgT[swz(nt * 16 + lr, 4 + lk)];
#pragma unroll
    for (int mt = 0; mt < 4; ++mt) {
      const int row = w * 64 + mt * 16 + lr;
      const bf16x8 a0 = *(const bf16x8*)&xs[swz(row, lk)];
      const bf16x8 a1 = *(const bf16x8*)&xs[swz(row, 4 + lk)];
      acc[mt][nt] = __builtin_amdgcn_mfma_f32_16x16x32_bf16(a0, b0, acc[mt][nt], 0, 0, 0);
      acc[mt][nt] = __builtin_amdgcn_mfma_f32_16x16x32_bf16(a1, b1, acc[mt][nt], 0, 0, 0);
    }
  }

  // epilogue1: og = sigmoid(z + bg) * o  -> back into xs (wave-private rows)
#pragma unroll
  for (int mt = 0; mt < 4; ++mt)
#pragma unroll
    for (int nt = 0; nt < 4; ++nt)
#pragma unroll
      for (int reg = 0; reg < 4; ++reg) {
        const float z = acc[mt][nt][reg] + bg4[nt];
        const float g = 1.0f / (1.0f + __expf(-z));
        const float og = g * o4[nt];
        const int row = w * 64 + mt * 16 + lk * 4 + reg;
        const int c = nt * 16 + lr;
        xs[row * 64 + (((c >> 3) ^ (row & 7)) << 3) + (c & 7)] = bf16r(og);
      }
  __syncthreads();   // make og writes visible (cross-lane within wave)

  // GEMM2: out = og @ w_o
  f32x4 acc2[4][4];
#pragma unroll
  for (int mt = 0; mt < 4; ++mt)
#pragma unroll
    for (int nt = 0; nt < 4; ++nt) acc2[mt][nt] = (f32x4)(0.f);
#pragma unroll
  for (int nt = 0; nt < 4; ++nt) {
    const bf16x8 b0 = *(const bf16x8*)&woT[swz(nt * 16 + lr, lk)];
    const bf16x8 b1 = *(const bf16x8*)&woT[swz(nt * 16 + lr, 4 + lk)];
#pragma unroll
    for (int mt = 0; mt < 4; ++mt) {
      const int row = w * 64 + mt * 16 + lr;
      const bf16x8 a0 = *(const bf16x8*)&xs[swz(row, lk)];
      const bf16x8 a1 = *(const bf16x8*)&xs[swz(row, 4 + lk)];
      acc2[mt][nt] = __builtin_amdgcn_mfma_f32_16x16x32_bf16(a0, b0, acc2[mt][nt], 0, 0, 0);
      acc2[mt][nt] = __builtin_amdgcn_mfma_f32_16x16x32_bf16(a1, b1, acc2[mt][nt], 0, 0, 0);
    }
  }

  // store out[n][r][c]
#pragma unroll
  for (int mt = 0; mt < 4; ++mt)
#pragma unroll
    for (int nt = 0; nt < 4; ++nt)
#pragma unroll
      for (int reg = 0; reg < 4; ++reg) {
        const int row = w * 64 + mt * 16 + lk * 4 + reg;
        const int c = nt * 16 + lr;
        out[((size_t)(n0 + row) * NR + r) * CI + c] = acc2[mt][nt][reg] + bo4[nt];
      }
}

// =====================================================================
extern "C" void kernel_launch(void* const* d_in, const int* in_sizes, int n_in,
                              void* d_out, int out_size, void* d_ws, size_t ws_size,
                              hipStream_t stream) {
  const float* m    = (const float*)d_in[0];
  const float* mask = (const float*)d_in[1];
  const float* lnw  = (const float*)d_in[2];
  const float* lnb  = (const float*)d_in[3];
  const float* wq   = (const float*)d_in[4];
  const float* wk   = (const float*)d_in[5];
  const float* wv   = (const float*)d_in[6];
  const float* wg   = (const float*)d_in[7];
  const float* bg   = (const float*)d_in[8];
  const float* wo   = (const float*)d_in[9];
  const float* bo   = (const float*)d_in[10];
  float* out = (float*)d_out;

  char* ws = (char*)d_ws;
  unsigned short* x_ws = (unsigned short*)ws;
  float* kv_ws = (float*)(ws + KV_OFF);
  float* qp_ws = (float*)(ws + QP_OFF);
  float* o_ws  = (float*)(ws + O_OFF);

  k1_ln_kv<<<dim3(8, 512), 256, 0, stream>>>(m, mask, lnw, lnb, wk, wv,
                                             x_ws, kv_ws, qp_ws);
  k2_attn<<<dim3(512), 256, 0, stream>>>(mask, wq, kv_ws, qp_ws, o_ws);
  k3_out<<<dim3(8, 512), 256, 0, stream>>>(x_ws, o_ws, wg, bg, wo, bo, out);
}